// Round 16
// baseline (70.396 us; speedup 1.0000x reference)
//
#include <hip/hip_runtime.h>
#include <hip/hip_bf16.h>

typedef __attribute__((ext_vector_type(4))) float f32x4;
typedef __attribute__((ext_vector_type(16))) float f32x16;
typedef __attribute__((ext_vector_type(8))) short bf16x8;
typedef __attribute__((ext_vector_type(4))) unsigned short u16x4;
typedef __attribute__((ext_vector_type(4))) int i32x4;
typedef __attribute__((ext_vector_type(4))) unsigned int u32x4;

// B=2, S=2048, D=1024, H=16, HD=64
#define SB 2048
#define DD 1024
#define NH 16
#define HD 64
#define BH 32   // B*H

#define A_SCALE 0.42466089f   // sqrt(0.125 * log2(e)); (aQ)(aQ)^T = 0.125*log2e * QQ^T

static __device__ __forceinline__ unsigned short f2bf(float f) {
    union { float f; unsigned int u; } v; v.f = f;
    unsigned int lsb = (v.u >> 16) & 1u;
    v.u += 0x7fffu + lsb;           // RNE (inputs finite)
    return (unsigned short)(v.u >> 16);
}

static __device__ __forceinline__ unsigned short f2bf_fast(float f) {
    __hip_bfloat16 h = __float2bfloat16(f);
    return *reinterpret_cast<unsigned short*>(&h);
}

static __device__ __forceinline__ float bf2f(unsigned short u) {
    union { unsigned int u; float f; } v; v.u = (unsigned int)u << 16;
    return v.f;
}

// swizzled read from an LDS tile with 128B rows: byte col ^= (row&7)<<4
static __device__ __forceinline__ bf16x8 ld_swz128(const unsigned short* base, int row, int colb) {
    return *reinterpret_cast<const bf16x8*>(
        reinterpret_cast<const char*>(base) + row * 128 + (colb ^ ((row & 7) << 4)));
}

// Stage ROUNDS*8KB from global into LDS via global_load_lds (16B/lane), 512 threads.
template<int ROUNDS>
static __device__ __forceinline__ void stage512(
    const char* gbase, int rowstrideB, unsigned short* lds, int tid)
{
    const int wave = tid >> 6;
    #pragma unroll
    for (int rd = 0; rd < ROUNDS; ++rd) {
        int c = rd * 512 + tid;        // 16B chunk index
        int r = c >> 3, j = c & 7;     // row, chunk-in-row
        const char* src = gbase + (size_t)r * rowstrideB + ((j ^ (r & 7)) * 16);
        __builtin_amdgcn_global_load_lds(
            (const __attribute__((address_space(1))) unsigned int*)src,
            (__attribute__((address_space(3))) unsigned int*)((char*)lds + rd * 8192 + wave * 1024),
            16, 0, 0);
    }
}

// ---------------- cvt: f32 -> bf16 for X, Wq (pre-scaled by A_SCALE), Wv ----------------
__global__ __launch_bounds__(256) void cvt_kernel(
    const float* __restrict__ X, const float* __restrict__ Wq,
    const float* __restrict__ Wv,
    unsigned short* __restrict__ Xb, unsigned short* __restrict__ Wb)
{
    int i = blockIdx.x * 256 + threadIdx.x;   // 8 elements per thread
    const float* src; unsigned short* dst; size_t off; float sc = 1.0f;
    if (i < 524288)      { src = X;  dst = Xb;            off = (size_t)i * 8; }
    else if (i < 655360) { src = Wq; dst = Wb;            off = (size_t)(i - 524288) * 8; sc = A_SCALE; }
    else                 { src = Wv; dst = Wb + 1048576;  off = (size_t)(i - 655360) * 8; }
    f32x4 a = *reinterpret_cast<const f32x4*>(src + off);
    f32x4 b = *reinterpret_cast<const f32x4*>(src + off + 4);
    u16x4 pa, pb;
    #pragma unroll
    for (int j = 0; j < 4; ++j) { pa[j] = f2bf(a[j] * sc); pb[j] = f2bf(b[j] * sc); }
    *reinterpret_cast<u16x4*>(dst + off)     = pa;
    *reinterpret_cast<u16x4*>(dst + off + 4) = pb;
}

// ---------------- proj2: C[4096,1024] = Xb @ Wb[z]^T (R11-proven: 128x128, 8-wave) ----------------
__global__ __launch_bounds__(512, 4) void proj2_kernel(
    const unsigned short* __restrict__ Xb,   // [4096][1024]
    const unsigned short* __restrict__ Wb,   // [2048][1024]  (Wq rows pre-scaled)
    unsigned short* __restrict__ qbf,        // [32][2048][64]
    unsigned short* __restrict__ vt)         // [32][64][2048]
{
    __shared__ unsigned short As[2][128 * 64];
    __shared__ unsigned short Bs[2][128 * 64];
    const int z  = blockIdx.z;
    const int m0 = blockIdx.y * 128;
    const int n0 = blockIdx.x * 128;
    const int tid = threadIdx.x;
    const int wave = tid >> 6, lane = tid & 63;
    const int wr = wave >> 2, wc = wave & 3;      // 2x4 waves, each 64x32
    const int lrow = lane & 15, lg = lane >> 4;

    const char* Ag = (const char*)Xb + (size_t)m0 * 2048;
    const char* Bg = (const char*)Wb + (size_t)(z * 1024 + n0) * 2048;

    f32x4 acc[4][2] = {};   // [mf][nf]

    stage512<2>(Ag, 2048, As[0], tid);
    stage512<2>(Bg, 2048, Bs[0], tid);

    int cur = 0;
    for (int kt = 0; kt < 16; ++kt) {
        if (kt + 1 < 16) {
            stage512<2>(Ag + (kt + 1) * 128, 2048, As[cur ^ 1], tid);
            stage512<2>(Bg + (kt + 1) * 128, 2048, Bs[cur ^ 1], tid);
            asm volatile("s_waitcnt vmcnt(4)" ::: "memory");   // this tile's 4 landed
        } else {
            asm volatile("s_waitcnt vmcnt(0)" ::: "memory");
        }
        __builtin_amdgcn_s_barrier();

        bf16x8 af[4][2], bf[2][2];
        #pragma unroll
        for (int mf = 0; mf < 4; ++mf)
            #pragma unroll
            for (int kk = 0; kk < 2; ++kk)
                af[mf][kk] = ld_swz128(As[cur], wr * 64 + mf * 16 + lrow, kk * 64 + lg * 16);
        #pragma unroll
        for (int nf = 0; nf < 2; ++nf)
            #pragma unroll
            for (int kk = 0; kk < 2; ++kk)
                bf[nf][kk] = ld_swz128(Bs[cur], wc * 32 + nf * 16 + lrow, kk * 64 + lg * 16);
        __builtin_amdgcn_s_setprio(1);
        #pragma unroll
        for (int kk = 0; kk < 2; ++kk)
            #pragma unroll
            for (int mf = 0; mf < 4; ++mf)
                #pragma unroll
                for (int nf = 0; nf < 2; ++nf)
                    acc[mf][nf] = __builtin_amdgcn_mfma_f32_16x16x32_bf16(
                        af[mf][kk], bf[nf][kk], acc[mf][nf], 0, 0, 0);
        __builtin_amdgcn_s_setprio(0);
        __builtin_amdgcn_s_barrier();
        cur ^= 1;
    }

    const int lcol = lane & 15, lr4 = (lane >> 4) * 4;
    #pragma unroll
    for (int mf = 0; mf < 4; ++mf) {
        #pragma unroll
        for (int nf = 0; nf < 2; ++nf) {
            #pragma unroll
            for (int r = 0; r < 4; ++r) {
                int gm = m0 + wr * 64 + mf * 16 + lr4 + r;
                int gn = n0 + wc * 32 + nf * 16 + lcol;
                int b = gm >> 11, s = gm & (SB - 1);
                int h = gn >> 6,  e = gn & (HD - 1);
                unsigned short bvx = f2bf(acc[mf][nf][r]);
                size_t bh = (size_t)(b * NH + h);
                if (z == 0) qbf[(bh * SB + s) * HD + e] = bvx;
                else        vt [(bh * HD + e) * SB + s] = bvx;
            }
        }
    }
}

// ---------------- attn: swapped QK^T, in-register softmax, PAIRED tiles ----------------
// grid (x=bh 32, y=parity 2, z: qb=15-z LPT); 256 thr = 4 waves x 32 q-rows = 128-row tile.
// Tiles processed in PAIRS with no barrier between pair members: 4 LDS slots
// (2 compute + 2 prefetch), ONE barrier per pair (halved vs R13). Tile-1's QK
// (MFMA/ds_read) overlaps tile-0's softmax (VALU) in the barrier-free region.
__global__ __launch_bounds__(256, 2) void attn_kernel(
    const unsigned short* __restrict__ qbf,  // [32][2048][64]  (Q pre-scaled)
    const unsigned short* __restrict__ vt,   // [32][64][2048]
    unsigned short* __restrict__ o0, unsigned short* __restrict__ o1,  // bf16 partials
    float* __restrict__ l0, float* __restrict__ l1)                    // [32][2048]
{
    __shared__ unsigned short Kl[4][4096];       // 4 slots x 8KB, swizzled [64 kv][128B]
    __shared__ unsigned short Vl[4][4096];

    const int bh = blockIdx.x;
    const int g  = blockIdx.y;                 // KV parity
    const int qb = 15 - (int)blockIdx.z;       // LPT: longest first
    const int tid  = threadIdx.x;
    const int lane = tid & 63;
    const int wave = tid >> 6;
    const int lq = lane & 31;                  // qrow-in-wave / e-col
    const int hi = lane >> 5;                  // k-half selector
    const int wq0 = qb * 128 + wave * 32;      // this wave's first q-row
    const int NT  = qb + 1;                    // tiles of my parity
    const int NP  = (NT + 1) >> 1;             // pairs
    const char* Qg = (const char*)(qbf + (size_t)bh * (SB * HD));
    const char* Vg = (const char*)(vt  + (size_t)bh * (HD * SB));
    const unsigned short* Qh = qbf + (size_t)bh * (SB * HD);

    // per-thread staging geometry: 2 chunks per 8KB [64][128B] tile
    int dsoff[2], vsrc[2], ksrc[2];
    #pragma unroll
    for (int c = 0; c < 2; ++c) {
        int slot = c * 4096 + tid * 16;
        int srow = slot >> 7, scolb = slot & 127;
        dsoff[c] = srow * 128 + (scolb ^ ((srow & 7) << 4));
        ksrc[c]  = slot;                   // K rows contiguous 128B
        vsrc[c]  = srow * 4096 + scolb;    // V^T rows stride 4096B
    }

    // Q B-frags: qf[s] = Q[wq0+lq][d = s*16 + hi*8 .. +7], s=0..3
    bf16x8 qf[4];
    #pragma unroll
    for (int s = 0; s < 4; ++s)
        qf[s] = *reinterpret_cast<const bf16x8*>(Qh + (wq0 + lq) * HD + s * 16 + hi * 8);

    f32x16 o_acc[2] = {};      // [e-half]; lane holds O[crow(r,hi)][eh*32+lq]
    float l_lane = 0.f;

    // one tile: QK^T (swapped) -> linear softmax -> cvt_pk/permlane pack -> PV
    auto do_tile = [&](const unsigned short* Kb, const unsigned short* Vb, int kv0) {
        if (kv0 > wq0 + 31) return;            // tile fully above my rows
        f32x16 sacc[2] = {};
        __builtin_amdgcn_s_setprio(1);
        #pragma unroll
        for (int h = 0; h < 2; ++h)
            #pragma unroll
            for (int s = 0; s < 4; ++s) {
                bf16x8 kf = ld_swz128(Kb, h * 32 + lq, s * 32 + hi * 16);
                sacc[h] = __builtin_amdgcn_mfma_f32_32x32x16_bf16(kf, qf[s], sacc[h], 0, 0, 0);
            }
        __builtin_amdgcn_s_setprio(0);

        if (kv0 + 63 > wq0) {                  // diagonal-crossing: mask col > row
            const int row = wq0 + lq;
            #pragma unroll
            for (int h = 0; h < 2; ++h)
                #pragma unroll
                for (int r = 0; r < 16; ++r) {
                    int col = kv0 + h * 32 + (r & 3) + 8 * (r >> 2) + 4 * hi;
                    float e = (col > row) ? 0.f : __builtin_amdgcn_exp2f(sacc[h][r]);
                    l_lane += e;
                    sacc[h][r] = e;
                }
        } else {
            #pragma unroll
            for (int h = 0; h < 2; ++h)
                #pragma unroll
                for (int r = 0; r < 16; ++r) {
                    float e = __builtin_amdgcn_exp2f(sacc[h][r]);
                    l_lane += e;
                    sacc[h][r] = e;
                }
        }

        unsigned int cw[2][8];
        #pragma unroll
        for (int h = 0; h < 2; ++h)
            #pragma unroll
            for (int m = 0; m < 8; ++m)
                asm("v_cvt_pk_bf16_f32 %0, %1, %2"
                    : "=v"(cw[h][m]) : "v"(sacc[h][2 * m]), "v"(sacc[h][2 * m + 1]));

        bf16x8 pa[4];
        #pragma unroll
        for (int ks = 0; ks < 4; ++ks) {
            const int h = ks >> 1, e4 = (ks & 1) * 4;
            unsigned int a0 = cw[h][e4 + 0], b0 = cw[h][e4 + 2];
            unsigned int a1 = cw[h][e4 + 1], b1 = cw[h][e4 + 3];
            asm("v_permlane32_swap_b32 %0, %1" : "+v"(a0), "+v"(b0));
            asm("v_permlane32_swap_b32 %0, %1" : "+v"(a1), "+v"(b1));
            u32x4 pw;
            pw[0] = a0; pw[1] = a1; pw[2] = b0; pw[3] = b1;
            pa[ks] = *reinterpret_cast<bf16x8*>(&pw);
        }

        __builtin_amdgcn_s_setprio(1);
        #pragma unroll
        for (int ks = 0; ks < 4; ++ks)
            #pragma unroll
            for (int eh = 0; eh < 2; ++eh) {
                bf16x8 vf = ld_swz128(Vb, eh * 32 + lq, ks * 32 + hi * 16);
                o_acc[eh] = __builtin_amdgcn_mfma_f32_32x32x16_bf16(pa[ks], vf, o_acc[eh], 0, 0, 0);
            }
        __builtin_amdgcn_s_setprio(0);
    };

    // prologue: stage tiles j=0 (and j=1 if present) into slots 0,1
    {
        #pragma unroll
        for (int c = 0; c < 2; ++c) {
            i32x4 rk = *reinterpret_cast<const i32x4*>(Qg + (size_t)g * 8192 + ksrc[c]);
            i32x4 rv = *reinterpret_cast<const i32x4*>(Vg + (size_t)g * 128 + vsrc[c]);
            *reinterpret_cast<i32x4*>((char*)&Kl[0][0] + dsoff[c]) = rk;
            *reinterpret_cast<i32x4*>((char*)&Vl[0][0] + dsoff[c]) = rv;
        }
        if (NT > 1) {
            const int t1 = g + 2;
            #pragma unroll
            for (int c = 0; c < 2; ++c) {
                i32x4 rk = *reinterpret_cast<const i32x4*>(Qg + (size_t)t1 * 8192 + ksrc[c]);
                i32x4 rv = *reinterpret_cast<const i32x4*>(Vg + (size_t)t1 * 128 + vsrc[c]);
                *reinterpret_cast<i32x4*>((char*)&Kl[1][0] + dsoff[c]) = rk;
                *reinterpret_cast<i32x4*>((char*)&Vl[1][0] + dsoff[c]) = rv;
            }
        }
    }
    __syncthreads();

    for (int p = 0; p < NP; ++p) {
        const int base = (p & 1) << 1;         // compute slots {base, base+1}
        const int nb   = 2 - base;             // prefetch slots {nb, nb+1}
        const int j1 = 2 * p + 1, j2 = 2 * p + 2, j3 = 2 * p + 3;

        // T14: issue next pair's loads NOW, consume after compute
        i32x4 rk2[2], rv2[2], rk3[2], rv3[2];
        if (j2 < NT) {
            const int t2 = g + 2 * j2;
            #pragma unroll
            for (int c = 0; c < 2; ++c) {
                rk2[c] = *reinterpret_cast<const i32x4*>(Qg + (size_t)t2 * 8192 + ksrc[c]);
                rv2[c] = *reinterpret_cast<const i32x4*>(Vg + (size_t)t2 * 128 + vsrc[c]);
            }
            if (j3 < NT) {
                const int t3 = g + 2 * j3;
                #pragma unroll
                for (int c = 0; c < 2; ++c) {
                    rk3[c] = *reinterpret_cast<const i32x4*>(Qg + (size_t)t3 * 8192 + ksrc[c]);
                    rv3[c] = *reinterpret_cast<const i32x4*>(Vg + (size_t)t3 * 128 + vsrc[c]);
                }
            }
        }

        // barrier-free pair: tile j0 then tile j1 (compiler interleaves chains)
        do_tile(Kl[base],     Vl[base],     (g + 4 * p) * 64);
        if (j1 < NT)
            do_tile(Kl[base + 1], Vl[base + 1], (g + 4 * p + 2) * 64);

        if (j2 < NT) {      // write next pair into the other slot pair
            #pragma unroll
            for (int c = 0; c < 2; ++c) {
                *reinterpret_cast<i32x4*>((char*)&Kl[nb][0] + dsoff[c]) = rk2[c];
                *reinterpret_cast<i32x4*>((char*)&Vl[nb][0] + dsoff[c]) = rv2[c];
            }
            if (j3 < NT) {
                #pragma unroll
                for (int c = 0; c < 2; ++c) {
                    *reinterpret_cast<i32x4*>((char*)&Kl[nb + 1][0] + dsoff[c]) = rk3[c];
                    *reinterpret_cast<i32x4*>((char*)&Vl[nb + 1][0] + dsoff[c]) = rv3[c];
                }
            }
            __syncthreads();    // one barrier per pair
        }
    }

    // l: combine the two k-halves (lanes l and l^32 hold partial sums for qrow lq)
    float l_full = l_lane + __shfl_xor(l_lane, 32);

    // store partials as bf16 (norm2 merges parities and divides)
    unsigned short* op = (g ? o1 : o0) + ((size_t)bh * SB + wq0) * HD;
    #pragma unroll
    for (int r = 0; r < 16; ++r) {
        int row = (r & 3) + 8 * (r >> 2) + 4 * hi;
        #pragma unroll
        for (int eh = 0; eh < 2; ++eh)
            op[(size_t)row * HD + eh * 32 + lq] = f2bf_fast(o_acc[eh][r]);
    }
    if (hi == 0) {
        float* lp = g ? l1 : l0;
        lp[(size_t)bh * SB + wq0 + lq] = l_full;
    }
}

// ---------------- norm2: out = (o0+o1)/(l0+l1), reshaped to [B][S][D] ----------------
__global__ __launch_bounds__(256) void norm2_kernel(
    float* __restrict__ out,
    const unsigned short* __restrict__ o0, const unsigned short* __restrict__ o1,
    const float* __restrict__ l0, const float* __restrict__ l1)
{
    int i = blockIdx.x * 256 + threadIdx.x;   // 1M vec4 groups
    int e4 = i << 2;
    int b = e4 >> 21;
    int s = (e4 >> 10) & (SB - 1);
    int h = (e4 >> 6) & (NH - 1);
    int e = e4 & (HD - 1);
    int bh = (b << 4) | h;
    size_t lidx = (size_t)bh * SB + s;
    size_t pidx = lidx * HD + e;
    float linv = 1.f / (l0[lidx] + l1[lidx]);
    u16x4 a = *reinterpret_cast<const u16x4*>(o0 + pidx);
    u16x4 c = *reinterpret_cast<const u16x4*>(o1 + pidx);
    f32x4 v;
    #pragma unroll
    for (int j = 0; j < 4; ++j) v[j] = (bf2f(a[j]) + bf2f(c[j])) * linv;
    *reinterpret_cast<f32x4*>(out + e4) = v;
}

extern "C" void kernel_launch(void* const* d_in, const int* in_sizes, int n_in,
                              void* d_out, int out_size, void* d_ws, size_t ws_size,
                              hipStream_t stream) {
    const float* X  = (const float*)d_in[0];
    const float* Wq = (const float*)d_in[1];
    // d_in[2] = Wk: computed-but-unused in the reference output -> skipped
    const float* Wv = (const float*)d_in[3];
    float* out = (float*)d_out;

    unsigned short* qbf = (unsigned short*)d_ws;                   // 8 MB
    unsigned short* vtp = qbf + (size_t)BH * SB * HD;              // 8 MB
    unsigned short* Xb  = vtp + (size_t)BH * HD * SB;              // 8 MB
    unsigned short* Wb  = Xb  + (size_t)2 * SB * DD;               // 4 MB
    unsigned short* o0  = Wb  + (size_t)SB * DD;                   // 8 MB (bf16)
    unsigned short* o1  = o0  + (size_t)BH * SB * HD;              // 8 MB (bf16)
    float* l0 = (float*)(o1 + (size_t)BH * SB * HD);               // 0.25 MB
    float* l1 = l0 + (size_t)BH * SB;                              // 0.25 MB

    cvt_kernel<<<dim3(3072), dim3(256), 0, stream>>>(X, Wq, Wv, Xb, Wb);
    proj2_kernel<<<dim3(8, 32, 2), dim3(512), 0, stream>>>(Xb, Wb, qbf, vtp);
    attn_kernel<<<dim3(32, 2, 16), dim3(256), 0, stream>>>(qbf, vtp, o0, o1, l0, l1);
    norm2_kernel<<<dim3((2 * SB * DD / 4) / 256), dim3(256), 0, stream>>>(out, o0, o1, l0, l1);
}

// Round 17
// 69.306 us; speedup vs baseline: 1.0157x; 1.0157x over previous
//
#include <hip/hip_runtime.h>
#include <hip/hip_bf16.h>

typedef __attribute__((ext_vector_type(4))) float f32x4;
typedef __attribute__((ext_vector_type(16))) float f32x16;
typedef __attribute__((ext_vector_type(8))) short bf16x8;
typedef __attribute__((ext_vector_type(4))) unsigned short u16x4;
typedef __attribute__((ext_vector_type(4))) int i32x4;
typedef __attribute__((ext_vector_type(4))) unsigned int u32x4;

// B=2, S=2048, D=1024, H=16, HD=64
#define SB 2048
#define DD 1024
#define NH 16
#define HD 64
#define BH 32   // B*H

#define A_SCALE 0.42466089f   // sqrt(0.125 * log2(e)); (aQ)(aQ)^T = 0.125*log2e * QQ^T

static __device__ __forceinline__ unsigned short f2bf(float f) {
    union { float f; unsigned int u; } v; v.f = f;
    unsigned int lsb = (v.u >> 16) & 1u;
    v.u += 0x7fffu + lsb;           // RNE (inputs finite)
    return (unsigned short)(v.u >> 16);
}

static __device__ __forceinline__ unsigned short f2bf_fast(float f) {
    __hip_bfloat16 h = __float2bfloat16(f);
    return *reinterpret_cast<unsigned short*>(&h);
}

static __device__ __forceinline__ float bf2f(unsigned short u) {
    union { unsigned int u; float f; } v; v.u = (unsigned int)u << 16;
    return v.f;
}

// swizzled read from an LDS tile with 128B rows: byte col ^= (row&7)<<4
static __device__ __forceinline__ bf16x8 ld_swz128(const unsigned short* base, int row, int colb) {
    return *reinterpret_cast<const bf16x8*>(
        reinterpret_cast<const char*>(base) + row * 128 + (colb ^ ((row & 7) << 4)));
}

// Stage ROUNDS*8KB from global into LDS via global_load_lds (16B/lane), 512 threads.
template<int ROUNDS>
static __device__ __forceinline__ void stage512(
    const char* gbase, int rowstrideB, unsigned short* lds, int tid)
{
    const int wave = tid >> 6;
    #pragma unroll
    for (int rd = 0; rd < ROUNDS; ++rd) {
        int c = rd * 512 + tid;        // 16B chunk index
        int r = c >> 3, j = c & 7;     // row, chunk-in-row
        const char* src = gbase + (size_t)r * rowstrideB + ((j ^ (r & 7)) * 16);
        __builtin_amdgcn_global_load_lds(
            (const __attribute__((address_space(1))) unsigned int*)src,
            (__attribute__((address_space(3))) unsigned int*)((char*)lds + rd * 8192 + wave * 1024),
            16, 0, 0);
    }
}

// ---------------- cvt: f32 -> bf16 for X, Wq (pre-scaled by A_SCALE), Wv ----------------
__global__ __launch_bounds__(256) void cvt_kernel(
    const float* __restrict__ X, const float* __restrict__ Wq,
    const float* __restrict__ Wv,
    unsigned short* __restrict__ Xb, unsigned short* __restrict__ Wb)
{
    int i = blockIdx.x * 256 + threadIdx.x;   // 8 elements per thread
    const float* src; unsigned short* dst; size_t off; float sc = 1.0f;
    if (i < 524288)      { src = X;  dst = Xb;            off = (size_t)i * 8; }
    else if (i < 655360) { src = Wq; dst = Wb;            off = (size_t)(i - 524288) * 8; sc = A_SCALE; }
    else                 { src = Wv; dst = Wb + 1048576;  off = (size_t)(i - 655360) * 8; }
    f32x4 a = *reinterpret_cast<const f32x4*>(src + off);
    f32x4 b = *reinterpret_cast<const f32x4*>(src + off + 4);
    u16x4 pa, pb;
    #pragma unroll
    for (int j = 0; j < 4; ++j) { pa[j] = f2bf(a[j] * sc); pb[j] = f2bf(b[j] * sc); }
    *reinterpret_cast<u16x4*>(dst + off)     = pa;
    *reinterpret_cast<u16x4*>(dst + off + 4) = pb;
}

// ---------------- proj2: C[4096,1024] = Xb @ Wb[z]^T (R11-proven: 128x128, 8-wave) ----------------
__global__ __launch_bounds__(512, 4) void proj2_kernel(
    const unsigned short* __restrict__ Xb,   // [4096][1024]
    const unsigned short* __restrict__ Wb,   // [2048][1024]  (Wq rows pre-scaled)
    unsigned short* __restrict__ qbf,        // [32][2048][64]
    unsigned short* __restrict__ vt)         // [32][64][2048]
{
    __shared__ unsigned short As[2][128 * 64];
    __shared__ unsigned short Bs[2][128 * 64];
    const int z  = blockIdx.z;
    const int m0 = blockIdx.y * 128;
    const int n0 = blockIdx.x * 128;
    const int tid = threadIdx.x;
    const int wave = tid >> 6, lane = tid & 63;
    const int wr = wave >> 2, wc = wave & 3;      // 2x4 waves, each 64x32
    const int lrow = lane & 15, lg = lane >> 4;

    const char* Ag = (const char*)Xb + (size_t)m0 * 2048;
    const char* Bg = (const char*)Wb + (size_t)(z * 1024 + n0) * 2048;

    f32x4 acc[4][2] = {};   // [mf][nf]

    stage512<2>(Ag, 2048, As[0], tid);
    stage512<2>(Bg, 2048, Bs[0], tid);

    int cur = 0;
    for (int kt = 0; kt < 16; ++kt) {
        if (kt + 1 < 16) {
            stage512<2>(Ag + (kt + 1) * 128, 2048, As[cur ^ 1], tid);
            stage512<2>(Bg + (kt + 1) * 128, 2048, Bs[cur ^ 1], tid);
            asm volatile("s_waitcnt vmcnt(4)" ::: "memory");   // this tile's 4 landed
        } else {
            asm volatile("s_waitcnt vmcnt(0)" ::: "memory");
        }
        __builtin_amdgcn_s_barrier();

        bf16x8 af[4][2], bf[2][2];
        #pragma unroll
        for (int mf = 0; mf < 4; ++mf)
            #pragma unroll
            for (int kk = 0; kk < 2; ++kk)
                af[mf][kk] = ld_swz128(As[cur], wr * 64 + mf * 16 + lrow, kk * 64 + lg * 16);
        #pragma unroll
        for (int nf = 0; nf < 2; ++nf)
            #pragma unroll
            for (int kk = 0; kk < 2; ++kk)
                bf[nf][kk] = ld_swz128(Bs[cur], wc * 32 + nf * 16 + lrow, kk * 64 + lg * 16);
        __builtin_amdgcn_s_setprio(1);
        #pragma unroll
        for (int kk = 0; kk < 2; ++kk)
            #pragma unroll
            for (int mf = 0; mf < 4; ++mf)
                #pragma unroll
                for (int nf = 0; nf < 2; ++nf)
                    acc[mf][nf] = __builtin_amdgcn_mfma_f32_16x16x32_bf16(
                        af[mf][kk], bf[nf][kk], acc[mf][nf], 0, 0, 0);
        __builtin_amdgcn_s_setprio(0);
        __builtin_amdgcn_s_barrier();
        cur ^= 1;
    }

    const int lcol = lane & 15, lr4 = (lane >> 4) * 4;
    #pragma unroll
    for (int mf = 0; mf < 4; ++mf) {
        #pragma unroll
        for (int nf = 0; nf < 2; ++nf) {
            #pragma unroll
            for (int r = 0; r < 4; ++r) {
                int gm = m0 + wr * 64 + mf * 16 + lr4 + r;
                int gn = n0 + wc * 32 + nf * 16 + lcol;
                int b = gm >> 11, s = gm & (SB - 1);
                int h = gn >> 6,  e = gn & (HD - 1);
                unsigned short bvx = f2bf(acc[mf][nf][r]);
                size_t bh = (size_t)(b * NH + h);
                if (z == 0) qbf[(bh * SB + s) * HD + e] = bvx;
                else        vt [(bh * HD + e) * SB + s] = bvx;
            }
        }
    }
}

// ---------------- attn: swapped QK^T (32x32x16), in-register softmax (T12) ----------------
// grid (x=bh 32, y=parity 2, z: qb=15-z LPT); 256 thr = 4 waves x 32 q-rows = 128-row tile.
// mfma(A=K, B=Q) -> lane holds S^T: qrow = lane&31, kv_local(r,hi) = (r&3)+8*(r>>2)+4*hi.
// P -> bf16 A-frags via 16 cvt_pk + 8 permlane32_swap (both outputs used; no select).
// Reg-staged T14 dbuf; partials stored as BF16 (halved traffic); norm2 merges.
__global__ __launch_bounds__(256, 3) void attn_kernel(
    const unsigned short* __restrict__ qbf,  // [32][2048][64]  (Q pre-scaled)
    const unsigned short* __restrict__ vt,   // [32][64][2048]
    unsigned short* __restrict__ o0, unsigned short* __restrict__ o1,  // bf16 partials
    float* __restrict__ l0, float* __restrict__ l1)                    // [32][2048]
{
    __shared__ unsigned short Kl[2][4096];       // 8KB per buf, swizzled [64 kv][128B]
    __shared__ unsigned short Vl[2][4096];       // 8KB per buf, swizzled [64 e][128B]

    const int bh = blockIdx.x;
    const int g  = blockIdx.y;                 // KV parity
    const int qb = 15 - (int)blockIdx.z;       // LPT: longest first
    const int tid  = threadIdx.x;
    const int wave = tid >> 6, lane = tid & 63;
    const int lq = lane & 31;                  // qrow-in-wave / e-col
    const int hi = lane >> 5;                  // k-half selector
    const int wq0 = qb * 128 + wave * 32;      // this wave's first q-row
    const int NT  = qb + 1;                    // tiles of my parity
    const char* Qg = (const char*)(qbf + (size_t)bh * (SB * HD));
    const char* Vg = (const char*)(vt  + (size_t)bh * (HD * SB));
    const unsigned short* Qh = qbf + (size_t)bh * (SB * HD);

    // per-thread staging geometry: 2 chunks per 8KB [64][128B] tile
    int dsoff[2], vsrc[2], ksrc[2];
    #pragma unroll
    for (int c = 0; c < 2; ++c) {
        int slot = c * 4096 + tid * 16;
        int srow = slot >> 7, scolb = slot & 127;
        dsoff[c] = srow * 128 + (scolb ^ ((srow & 7) << 4));
        ksrc[c]  = slot;                   // K rows contiguous 128B
        vsrc[c]  = srow * 4096 + scolb;    // V^T rows stride 4096B
    }

    // Q B-frags: qf[s] = Q[wq0+lq][d = s*16 + hi*8 .. +7], s=0..3
    bf16x8 qf[4];
    #pragma unroll
    for (int s = 0; s < 4; ++s)
        qf[s] = *reinterpret_cast<const bf16x8*>(Qh + (wq0 + lq) * HD + s * 16 + hi * 8);

    // prologue: stage tile t=g into buf 0
    {
        #pragma unroll
        for (int c = 0; c < 2; ++c) {
            i32x4 rk = *reinterpret_cast<const i32x4*>(Qg + (size_t)g * 8192 + ksrc[c]);
            i32x4 rv = *reinterpret_cast<const i32x4*>(Vg + (size_t)g * 128 + vsrc[c]);
            *reinterpret_cast<i32x4*>((char*)&Kl[0][0] + dsoff[c]) = rk;
            *reinterpret_cast<i32x4*>((char*)&Vl[0][0] + dsoff[c]) = rv;
        }
    }
    __syncthreads();

    f32x16 o_acc[2] = {};      // [e-half]; lane holds O[crow(r,hi)][eh*32+lq]
    float l_lane = 0.f;
    int cur = 0;

    for (int i = 0; i < NT; ++i) {
        const int kv0 = (g + 2 * i) * 64;
        const bool pf = (i + 1 < NT);
        i32x4 rk[2], rv[2];
        if (pf) {   // T14: issue next parity tile's loads NOW, consume after compute
            const int tn = g + 2 * (i + 1);
            #pragma unroll
            for (int c = 0; c < 2; ++c) {
                rk[c] = *reinterpret_cast<const i32x4*>(Qg + (size_t)tn * 8192 + ksrc[c]);
                rv[c] = *reinterpret_cast<const i32x4*>(Vg + (size_t)tn * 128 + vsrc[c]);
            }
        }

        if (kv0 <= wq0 + 31) {                 // tile not fully above my rows
            // QK^T swapped: sacc[h] = K(half h) . Q  -> S^T fragments
            f32x16 sacc[2] = {};
            __builtin_amdgcn_s_setprio(1);
            #pragma unroll
            for (int h = 0; h < 2; ++h)
                #pragma unroll
                for (int s = 0; s < 4; ++s) {
                    bf16x8 kf = ld_swz128(Kl[cur], h * 32 + lq, s * 32 + hi * 16);
                    sacc[h] = __builtin_amdgcn_mfma_f32_32x32x16_bf16(kf, qf[s], sacc[h], 0, 0, 0);
                }
            __builtin_amdgcn_s_setprio(0);

            // p = exp2(s) in place; accumulate l per lane (linear softmax, f32-safe)
            if (kv0 + 63 > wq0) {              // diagonal-crossing: mask col > row
                const int row = wq0 + lq;
                #pragma unroll
                for (int h = 0; h < 2; ++h)
                    #pragma unroll
                    for (int r = 0; r < 16; ++r) {
                        int col = kv0 + h * 32 + (r & 3) + 8 * (r >> 2) + 4 * hi;
                        float e = (col > row) ? 0.f : __builtin_amdgcn_exp2f(sacc[h][r]);
                        l_lane += e;
                        sacc[h][r] = e;
                    }
            } else {
                #pragma unroll
                for (int h = 0; h < 2; ++h)
                    #pragma unroll
                    for (int r = 0; r < 16; ++r) {
                        float e = __builtin_amdgcn_exp2f(sacc[h][r]);
                        l_lane += e;
                        sacc[h][r] = e;
                    }
            }

            // pack pairs: cw[h][m] = cvt_pk(p[2m], p[2m+1])
            unsigned int cw[2][8];
            #pragma unroll
            for (int h = 0; h < 2; ++h)
                #pragma unroll
                for (int m = 0; m < 8; ++m)
                    asm("v_cvt_pk_bf16_f32 %0, %1, %2"
                        : "=v"(cw[h][m]) : "v"(sacc[h][2 * m]), "v"(sacc[h][2 * m + 1]));

            // build PA frags: pa[ks] holds P[lq][ks*16 + hi*8 + 0..7].
            // permlane32_swap(a,b): a' = {lo: own a, hi: b from lane-32},
            //                       b' = {lo: a from lane+32, hi: own b}.
            // Needed words are exactly {a0',a1',b0',b1'} for BOTH halves (no select).
            bf16x8 pa[4];
            #pragma unroll
            for (int ks = 0; ks < 4; ++ks) {
                const int h = ks >> 1, e4 = (ks & 1) * 4;
                unsigned int a0 = cw[h][e4 + 0], b0 = cw[h][e4 + 2];
                unsigned int a1 = cw[h][e4 + 1], b1 = cw[h][e4 + 3];
                asm("v_permlane32_swap_b32 %0, %1" : "+v"(a0), "+v"(b0));
                asm("v_permlane32_swap_b32 %0, %1" : "+v"(a1), "+v"(b1));
                u32x4 pw;
                pw[0] = a0;
                pw[1] = a1;
                pw[2] = b0;
                pw[3] = b1;
                pa[ks] = *reinterpret_cast<bf16x8*>(&pw);
            }

            // PV: O[qrow][e] += P . V  (B = V^T frags from swizzled LDS)
            __builtin_amdgcn_s_setprio(1);
            #pragma unroll
            for (int ks = 0; ks < 4; ++ks)
                #pragma unroll
                for (int eh = 0; eh < 2; ++eh) {
                    bf16x8 vf = ld_swz128(Vl[cur], eh * 32 + lq, ks * 32 + hi * 16);
                    o_acc[eh] = __builtin_amdgcn_mfma_f32_32x32x16_bf16(pa[ks], vf, o_acc[eh], 0, 0, 0);
                }
            __builtin_amdgcn_s_setprio(0);
        }

        if (pf) {   // write next tile into the other buffer
            const int nb = cur ^ 1;
            #pragma unroll
            for (int c = 0; c < 2; ++c) {
                *reinterpret_cast<i32x4*>((char*)&Kl[nb][0] + dsoff[c]) = rk[c];
                *reinterpret_cast<i32x4*>((char*)&Vl[nb][0] + dsoff[c]) = rv[c];
            }
            __syncthreads();
        }
        cur ^= 1;
    }

    // l: combine the two k-halves (lanes l and l^32 hold partial sums for qrow lq)
    float l_full = l_lane + __shfl_xor(l_lane, 32);

    // store partials as bf16 (norm2 merges parities and divides)
    unsigned short* op = (g ? o1 : o0) + ((size_t)bh * SB + wq0) * HD;
    #pragma unroll
    for (int r = 0; r < 16; ++r) {
        int row = (r & 3) + 8 * (r >> 2) + 4 * hi;
        #pragma unroll
        for (int eh = 0; eh < 2; ++eh)
            op[(size_t)row * HD + eh * 32 + lq] = f2bf_fast(o_acc[eh][r]);
    }
    if (hi == 0) {
        float* lp = g ? l1 : l0;
        lp[(size_t)bh * SB + wq0 + lq] = l_full;
    }
}

// ---------------- norm2: out = (o0+o1)/(l0+l1), reshaped to [B][S][D] ----------------
__global__ __launch_bounds__(256) void norm2_kernel(
    float* __restrict__ out,
    const unsigned short* __restrict__ o0, const unsigned short* __restrict__ o1,
    const float* __restrict__ l0, const float* __restrict__ l1)
{
    int i = blockIdx.x * 256 + threadIdx.x;   // 1M vec4 groups
    int e4 = i << 2;
    int b = e4 >> 21;
    int s = (e4 >> 10) & (SB - 1);
    int h = (e4 >> 6) & (NH - 1);
    int e = e4 & (HD - 1);
    int bh = (b << 4) | h;
    size_t lidx = (size_t)bh * SB + s;
    size_t pidx = lidx * HD + e;
    float linv = 1.f / (l0[lidx] + l1[lidx]);
    u16x4 a = *reinterpret_cast<const u16x4*>(o0 + pidx);
    u16x4 c = *reinterpret_cast<const u16x4*>(o1 + pidx);
    f32x4 v;
    #pragma unroll
    for (int j = 0; j < 4; ++j) v[j] = (bf2f(a[j]) + bf2f(c[j])) * linv;
    *reinterpret_cast<f32x4*>(out + e4) = v;
}

extern "C" void kernel_launch(void* const* d_in, const int* in_sizes, int n_in,
                              void* d_out, int out_size, void* d_ws, size_t ws_size,
                              hipStream_t stream) {
    const float* X  = (const float*)d_in[0];
    const float* Wq = (const float*)d_in[1];
    // d_in[2] = Wk: computed-but-unused in the reference output -> skipped
    const float* Wv = (const float*)d_in[3];
    float* out = (float*)d_out;

    unsigned short* qbf = (unsigned short*)d_ws;                   // 8 MB
    unsigned short* vtp = qbf + (size_t)BH * SB * HD;              // 8 MB
    unsigned short* Xb  = vtp + (size_t)BH * HD * SB;              // 8 MB
    unsigned short* Wb  = Xb  + (size_t)2 * SB * DD;               // 4 MB
    unsigned short* o0  = Wb  + (size_t)SB * DD;                   // 8 MB (bf16)
    unsigned short* o1  = o0  + (size_t)BH * SB * HD;              // 8 MB (bf16)
    float* l0 = (float*)(o1 + (size_t)BH * SB * HD);               // 0.25 MB
    float* l1 = l0 + (size_t)BH * SB;                              // 0.25 MB

    cvt_kernel<<<dim3(3072), dim3(256), 0, stream>>>(X, Wq, Wv, Xb, Wb);
    proj2_kernel<<<dim3(8, 32, 2), dim3(512), 0, stream>>>(Xb, Wb, qbf, vtp);
    attn_kernel<<<dim3(32, 2, 16), dim3(256), 0, stream>>>(qbf, vtp, o0, o1, l0, l1);
    norm2_kernel<<<dim3((2 * SB * DD / 4) / 256), dim3(256), 0, stream>>>(out, o0, o1, l0, l1);
}